// Round 2
// 245.146 us; speedup vs baseline: 1.0187x; 1.0187x over previous
//
#include <hip/hip_runtime.h>
#include <hip/hip_bf16.h>

// B=4, T=2048, C=1024 single-head causal attention, fp32 in/out.
// R10: revert QKV to the proven R8 gemm_bt core (the R9 counted-vmcnt
// pipeline raced under graph replay). New: V-transpose fused into the QKV
// epilogue — blocks covering cols 2048..3071 store acc directly into
// vT[b][d][t] (bh4 8B stores); transpose_v kernel removed.

typedef short bf16x8 __attribute__((ext_vector_type(8)));
typedef float f32x4  __attribute__((ext_vector_type(4)));

#define T_SEQ 2048
#define EMB   1024
#define NBAT  4

struct alignas(8) bh4 { __hip_bfloat16 a, b, c, d; };

__device__ __forceinline__ bh4 pack4(float x, float y, float z, float w) {
    bh4 o { __float2bfloat16(x), __float2bfloat16(y),
            __float2bfloat16(z), __float2bfloat16(w) };
    return o;
}

// ---------------------------------------------------------------- merged cast
__global__ void cast_all(const float* __restrict__ x,
                         const float* __restrict__ w0,
                         const float* __restrict__ w1,
                         const float* __restrict__ w2,
                         __hip_bfloat16* __restrict__ xb,
                         __hip_bfloat16* __restrict__ wb,
                         float* __restrict__ Lbuf) {
    const int bid = blockIdx.x;
    if (bid < 8192) {
        int i = bid * 256 + threadIdx.x;
        float4 v = reinterpret_cast<const float4*>(x)[i];
        reinterpret_cast<bh4*>(xb)[i] = pack4(v.x, v.y, v.z, v.w);
    } else if (bid < 11264) {
        int j = bid - 8192;                       // 0..3071
        int sel = j >> 10;
        const float* src = (sel == 0) ? w0 : (sel == 1) ? w1 : w2;
        int i = (j & 1023) * 256 + threadIdx.x;
        float4 v = reinterpret_cast<const float4*>(src)[i];
        reinterpret_cast<bh4*>(wb + (size_t)sel * 1048576)[i] =
            pack4(v.x, v.y, v.z, v.w);
    } else {
        Lbuf[(bid - 11264) * 256 + threadIdx.x] = 0.f;
    }
}

// ---------------------------------------------------------------- gemm core
__device__ __forceinline__ void load_lds16(const void* g, void* l) {
    __builtin_amdgcn_global_load_lds(
        (const __attribute__((address_space(1))) void*)g,
        (__attribute__((address_space(3))) void*)l, 16, 0, 0);
}

// S-triangle slab tables: half0 rts {12..15, 0..3}, half1 {8..11, 4..7};
// counts are rt+1 (68 tiles per (batch, half) group).
__device__ __constant__ int S_RT0[8] = {12, 13, 14, 15, 0, 1, 2, 3};
__device__ __constant__ int S_RT1[8] = {8, 9, 10, 11, 4, 5, 6, 7};

// C[M,N] = A[M,K]*B[N,K]^T, 128x128 tile, 4 waves, BK=64 (2x 32-k subtiles).
// EPI: 1 = plain bf16 store (QKV) with V cols (ct>=16) redirected transposed
//          into vTout[b][d][t].
//      3 = exp(s/32) masked bf16 + atomic rowsum.
// SWZ: 1 = XCD-slab 1536-block QKV.  3 = XCD-grouped triangle (544 blocks).
template<int EPI, int SWZ>
__global__ __launch_bounds__(256) void gemm_bt(
    const __hip_bfloat16* __restrict__ Abase,
    const __hip_bfloat16* __restrict__ Bbase,
    void* __restrict__ Cbase,
    float* __restrict__ Lbuf,
    __hip_bfloat16* __restrict__ vTout,
    int K, int lda, int ldb, int ldc,
    long batchA, long batchB, long batchC)
{
    int ct, rt, bz;
    if (SWZ == 1) {
        const int bid = blockIdx.x;
        const int xcd = bid & 7;
        const int ii  = bid >> 3;            // 0..191
        rt = (xcd << 3) | (ii & 7);          // 0..63
        ct = ii >> 3;                        // 0..23
        bz = 0;
    } else {                                  // SWZ == 3: XCD-grouped triangle
        const int bid = blockIdx.x;           // 0..543
        const int xcd = bid & 7;
        bz = xcd >> 1;
        const int* rts = (xcd & 1) ? S_RT1 : S_RT0;
        int idx = bid >> 3;                   // 0..67
        int seg = 0;
        while (idx >= rts[seg] + 1) { idx -= rts[seg] + 1; ++seg; }
        rt = rts[seg];
        ct = idx;
    }

    __shared__ short lsA[2][128 * 32];
    __shared__ short lsB[2][128 * 32];

    const int tid  = threadIdx.x;
    const int wave = tid >> 6;
    const int lane = tid & 63;
    const int wr   = (wave >> 1) * 64;
    const int wc   = (wave &  1) * 64;
    const int srow = wave * 32 + (lane >> 2);
    const int scol = (lane & 3) * 8;
    const int frow = lane & 15;
    const int fk   = (lane >> 4) * 8;

    const short* A = (const short*)Abase + bz * batchA + (long)rt * 128 * lda;
    const short* B = (const short*)Bbase + bz * batchB + (long)ct * 128 * ldb;

    f32x4 acc[4][4] = {};

    for (int k0 = 0; k0 < K; k0 += 64) {
        const short* ga = A + (long)srow * lda + k0 + scol;
        const short* gb = B + (long)srow * ldb + k0 + scol;
        load_lds16(ga,                  &lsA[0][(wave * 32) * 32]);
        load_lds16(ga + 16L * lda,      &lsA[0][(wave * 32 + 16) * 32]);
        load_lds16(ga + 32,             &lsA[1][(wave * 32) * 32]);
        load_lds16(ga + 16L * lda + 32, &lsA[1][(wave * 32 + 16) * 32]);
        load_lds16(gb,                  &lsB[0][(wave * 32) * 32]);
        load_lds16(gb + 16L * ldb,      &lsB[0][(wave * 32 + 16) * 32]);
        load_lds16(gb + 32,             &lsB[1][(wave * 32) * 32]);
        load_lds16(gb + 16L * ldb + 32, &lsB[1][(wave * 32 + 16) * 32]);
        __syncthreads();

        #pragma unroll
        for (int sub = 0; sub < 2; ++sub) {
            bf16x8 af[4], bfr[4];
            #pragma unroll
            for (int m = 0; m < 4; ++m)
                af[m] = *(const bf16x8*)&lsA[sub][(wr + m * 16 + frow) * 32 + fk];
            #pragma unroll
            for (int n = 0; n < 4; ++n)
                bfr[n] = *(const bf16x8*)&lsB[sub][(wc + n * 16 + frow) * 32 + fk];
            #pragma unroll
            for (int m = 0; m < 4; ++m)
                #pragma unroll
                for (int n = 0; n < 4; ++n)
                    acc[m][n] = __builtin_amdgcn_mfma_f32_16x16x32_bf16(
                        af[m], bfr[n], acc[m][n], 0, 0, 0);
        }
        __syncthreads();
    }

    // epilogue: C/D layout col = lane&15, row = (lane>>4)*4 + reg
    const long crow0 = (long)rt * 128 + wr;
    const long ccol0 = (long)ct * 128 + wc;
    const int  orow  = (lane >> 4) * 4;
    const int  ocol  = lane & 15;

    if (EPI == 1) {
        if (SWZ == 1 && ct >= 16) {
            // V columns: store transposed into vT[b][d][t] (d = col-2048).
            // Per (m,n): 4 consecutive t per lane -> one 8B bh4 store.
            #pragma unroll
            for (int m = 0; m < 4; ++m) {
                const long rowb = crow0 + m * 16 + orow;   // multiple of 4
                const long b    = rowb >> 11;
                const long t0   = rowb & 2047;
                #pragma unroll
                for (int n = 0; n < 4; ++n) {
                    const long d = ccol0 + n * 16 + ocol - 2048;
                    bh4 pk = pack4(acc[m][n][0], acc[m][n][1],
                                   acc[m][n][2], acc[m][n][3]);
                    *(bh4*)&vTout[((b << 10) + d) * 2048 + t0] = pk;
                }
            }
        } else {                              // Q/K columns: plain row store
            __hip_bfloat16* C = (__hip_bfloat16*)Cbase;
            #pragma unroll
            for (int m = 0; m < 4; ++m)
                #pragma unroll
                for (int n = 0; n < 4; ++n)
                    #pragma unroll
                    for (int r = 0; r < 4; ++r)
                        C[(crow0 + m * 16 + orow + r) * ldc + ccol0 + n * 16 + ocol] =
                            __float2bfloat16(acc[m][n][r]);
        }
    } else {                                  // EPI == 3: exp + mask + rowsum
        __hip_bfloat16* C = (__hip_bfloat16*)Cbase + bz * batchC;
        float rsum[4][4];
        #pragma unroll
        for (int m = 0; m < 4; ++m)
            #pragma unroll
            for (int r = 0; r < 4; ++r) rsum[m][r] = 0.f;
        #pragma unroll
        for (int m = 0; m < 4; ++m)
            #pragma unroll
            for (int n = 0; n < 4; ++n)
                #pragma unroll
                for (int r = 0; r < 4; ++r) {
                    const long row = crow0 + m * 16 + orow + r;
                    const long col = ccol0 + n * 16 + ocol;
                    float p = (col <= row) ? __expf(acc[m][n][r] * 0.03125f) : 0.f;
                    C[row * ldc + col] = __float2bfloat16(p);
                    rsum[m][r] += p;
                }
        #pragma unroll
        for (int m = 0; m < 4; ++m)
            #pragma unroll
            for (int r = 0; r < 4; ++r) {
                float v = rsum[m][r];
                v += __shfl_xor(v, 1);
                v += __shfl_xor(v, 2);
                v += __shfl_xor(v, 4);
                v += __shfl_xor(v, 8);
                if ((lane & 15) == 0)
                    atomicAdd(&Lbuf[bz * T_SEQ + crow0 + m * 16 + orow + r], v);
            }
    }
}

// ---------------------------------------------------------------- PV split-K
// 768 blocks = 8 XCD-groups x 96. xcd -> (bz = xcd>>1, half = xcd&1).
// idx = bid>>3: p = idx>>3 (0..11), ct = idx&7.
// half0: p<8  -> direct rt=p, full K, scaled -> d_out  (vT t<1024 only)
//        p>=8 -> part0 rt=p (8..11), K tiles [0,8)     -> d_out unscaled
// half1: p<4  -> part0 rt=12+p, K tiles [0,8)          -> d_out unscaled
//        p>=4 -> part1 rt=8+(p-4)=4+p, K [1024,(rt+1)*128) -> tmp1
// Both halves: 68 K-tiles of work. pv_finish combines rows >= 1024.
__global__ __launch_bounds__(256) void pv_split(
    const __hip_bfloat16* __restrict__ P,
    const __hip_bfloat16* __restrict__ Vt,
    float* __restrict__ out,
    float* __restrict__ tmp1,
    const float* __restrict__ Lbuf)
{
    const int bid  = blockIdx.x;             // 0..767
    const int xcd  = bid & 7;
    const int bz   = xcd >> 1;
    const int half = xcd & 1;
    const int idx  = bid >> 3;               // 0..95
    const int p    = idx >> 3;               // 0..11
    const int ct   = idx & 7;

    int rt, k0s, k0e;
    bool scaled = false;
    float* dst;
    if (half == 0) {
        if (p < 8) {
            rt = p; k0s = 0; k0e = (rt + 1) * 128; scaled = true;
            dst = out + (long)bz * 2097152 + (long)rt * 128 * 1024;
        } else {
            rt = p;  // 8..11
            k0s = 0; k0e = 1024;
            dst = out + (long)bz * 2097152 + (long)rt * 128 * 1024;
        }
    } else {
        if (p < 4) {
            rt = 12 + p; k0s = 0; k0e = 1024;
            dst = out + (long)bz * 2097152 + (long)rt * 128 * 1024;
        } else {
            rt = 4 + p;  // 8..15
            k0s = 1024; k0e = (rt + 1) * 128;
            dst = tmp1 + ((long)bz * 1024 + (long)(rt - 8) * 128) * 1024;
        }
    }

    __shared__ short lsA[2][128 * 32];
    __shared__ short lsB[2][128 * 32];

    const int tid  = threadIdx.x;
    const int wave = tid >> 6;
    const int lane = tid & 63;
    const int wr   = (wave >> 1) * 64;
    const int wc   = (wave &  1) * 64;
    const int srow = wave * 32 + (lane >> 2);
    const int scol = (lane & 3) * 8;
    const int frow = lane & 15;
    const int fk   = (lane >> 4) * 8;

    const short* A = (const short*)P  + (long)bz * 4194304 + (long)rt * 128 * 2048;
    const short* B = (const short*)Vt + (long)bz * 2097152 + (long)ct * 128 * 2048;

    f32x4 acc[4][4] = {};

    for (int k0 = k0s; k0 < k0e; k0 += 64) {
        const short* ga = A + (long)srow * 2048 + k0 + scol;
        const short* gb = B + (long)srow * 2048 + k0 + scol;
        load_lds16(ga,                   &lsA[0][(wave * 32) * 32]);
        load_lds16(ga + 16L * 2048,      &lsA[0][(wave * 32 + 16) * 32]);
        load_lds16(ga + 32,              &lsA[1][(wave * 32) * 32]);
        load_lds16(ga + 16L * 2048 + 32, &lsA[1][(wave * 32 + 16) * 32]);
        load_lds16(gb,                   &lsB[0][(wave * 32) * 32]);
        load_lds16(gb + 16L * 2048,      &lsB[0][(wave * 32 + 16) * 32]);
        load_lds16(gb + 32,              &lsB[1][(wave * 32) * 32]);
        load_lds16(gb + 16L * 2048 + 32, &lsB[1][(wave * 32 + 16) * 32]);
        __syncthreads();

        #pragma unroll
        for (int sub = 0; sub < 2; ++sub) {
            bf16x8 af[4], bfr[4];
            #pragma unroll
            for (int m = 0; m < 4; ++m)
                af[m] = *(const bf16x8*)&lsA[sub][(wr + m * 16 + frow) * 32 + fk];
            #pragma unroll
            for (int n = 0; n < 4; ++n)
                bfr[n] = *(const bf16x8*)&lsB[sub][(wc + n * 16 + frow) * 32 + fk];
            #pragma unroll
            for (int m = 0; m < 4; ++m)
                #pragma unroll
                for (int n = 0; n < 4; ++n)
                    acc[m][n] = __builtin_amdgcn_mfma_f32_16x16x32_bf16(
                        af[m], bfr[n], acc[m][n], 0, 0, 0);
        }
        __syncthreads();
    }

    const int orow = (lane >> 4) * 4;
    const int ocol = lane & 15;
    if (scaled) {
        const float* il = Lbuf + bz * T_SEQ + (long)rt * 128;
        #pragma unroll
        for (int m = 0; m < 4; ++m)
            #pragma unroll
            for (int r = 0; r < 4; ++r) {
                const long lrow = wr + m * 16 + orow + r;
                const float s = 1.f / il[lrow];
                #pragma unroll
                for (int n = 0; n < 4; ++n)
                    dst[lrow * 1024 + ct * 128 + wc + n * 16 + ocol] =
                        acc[m][n][r] * s;
            }
    } else {
        #pragma unroll
        for (int m = 0; m < 4; ++m)
            #pragma unroll
            for (int r = 0; r < 4; ++r) {
                const long lrow = wr + m * 16 + orow + r;
                #pragma unroll
                for (int n = 0; n < 4; ++n)
                    dst[lrow * 1024 + ct * 128 + wc + n * 16 + ocol] = acc[m][n][r];
            }
    }
}

// ---------------------------------------------------------------- PV finish
// rows >= 1024 per batch: out = (out + tmp1) / l.
__global__ void pv_finish(float* __restrict__ out,
                          const float* __restrict__ tmp1,
                          const float* __restrict__ Lbuf) {
    const int g = blockIdx.x;                // 0..4095
    const int b = g >> 10;
    const int r = (g & 1023) + 1024;
    const int c = threadIdx.x * 4;
    const float s = 1.f / Lbuf[b * T_SEQ + r];
    float* po = out + (long)b * 2097152 + (long)r * 1024 + c;
    float4 o = *(const float4*)po;
    float4 t = *(const float4*)&tmp1[((long)b * 1024 + (r - 1024)) * 1024 + c];
    o.x = (o.x + t.x) * s; o.y = (o.y + t.y) * s;
    o.z = (o.z + t.z) * s; o.w = (o.w + t.w) * s;
    *(float4*)po = o;
}

// ---------------------------------------------------------------- launch
extern "C" void kernel_launch(void* const* d_in, const int* in_sizes, int n_in,
                              void* d_out, int out_size, void* d_ws, size_t ws_size,
                              hipStream_t stream) {
    const float* x  = (const float*)d_in[0];
    const float* Wq = (const float*)d_in[1];
    const float* Wk = (const float*)d_in[2];
    const float* Wv = (const float*)d_in[3];

    char* ws = (char*)d_ws;
    // workspace (bytes):
    //   xb   @ 0         : 16,777,216   (dead after QKV; tmp1 aliases)
    //   wb   @ 16777216  :  6,291,456
    //   qkv  @ 23068672  : 50,331,648   (Q|K cols used; V cols unwritten)
    //   vT   @ 73400320  : 16,777,216
    //   P    @ 90177536  : 33,554,432
    //   l    @ 123731968 :     32,768
    __hip_bfloat16* xb   = (__hip_bfloat16*)(ws);
    __hip_bfloat16* wb   = (__hip_bfloat16*)(ws + 16777216);
    __hip_bfloat16* qkv  = (__hip_bfloat16*)(ws + 23068672);
    __hip_bfloat16* vT   = (__hip_bfloat16*)(ws + 73400320);
    __hip_bfloat16* P    = (__hip_bfloat16*)(ws + 90177536);
    float*          Lbuf = (float*)        (ws + 123731968);
    float*          tmp1 = (float*)        (ws);              // aliases xb

    // 1) casts + Lbuf zero
    cast_all<<<dim3(11296), 256, 0, stream>>>(x, Wq, Wk, Wv, xb, wb, Lbuf);

    // 2) fused QKV; Q/K rows -> qkv, V -> vT transposed in-epilogue
    gemm_bt<1, 1><<<dim3(1536), 256, 0, stream>>>(
        xb, wb, qkv, nullptr, vT,
        /*K*/1024, /*lda*/1024, /*ldb*/1024, /*ldc*/3072,
        0L, 0L, 0L);

    // 3) P = exp(mask(QK^T)/32) bf16 + atomic rowsums, XCD-grouped triangle
    gemm_bt<3, 3><<<dim3(544), 256, 0, stream>>>(
        qkv, qkv + 1024, P, Lbuf, nullptr,
        /*K*/1024, /*lda*/3072, /*ldb*/3072, /*ldc*/2048,
        /*bA*/6291456L, /*bB*/6291456L, /*bC*/4194304L);

    // 4) O = P @ V ; XCD-grouped split-K, direct rows scaled in-epilogue
    pv_split<<<dim3(768), 256, 0, stream>>>(
        P, vT, (float*)d_out, tmp1, Lbuf);

    // 5) combine + scale split rows
    pv_finish<<<dim3(4096), 256, 0, stream>>>((float*)d_out, tmp1, Lbuf);
}

// Round 3
// 241.611 us; speedup vs baseline: 1.0336x; 1.0146x over previous
//
#include <hip/hip_runtime.h>
#include <hip/hip_bf16.h>

// B=4, T=2048, C=1024 single-head causal attention, fp32 in/out.
// R11: T2 bank-conflict swizzle on all three GEMM cores. Physical 16B slot =
// logical slot ^ ((row>>1)&3); linear gload_lds dest + inverse-swizzled
// global SOURCE column (rule 21) + swizzled ds_read slot. Collapses to:
//   scol = ((lane&3) ^ ((lane>>3)&3)) * 8    (staging source)
//   fk   = ((lane>>4) ^ ((lane>>1)&3)) * 8   (fragment read)
// Every 16-lane read group covers all 8 bank-quads exactly 2x (free).
// Sync structure untouched (proven __syncthreads 2-phase core).

typedef short bf16x8 __attribute__((ext_vector_type(8)));
typedef float f32x4  __attribute__((ext_vector_type(4)));

#define T_SEQ 2048
#define EMB   1024
#define NBAT  4

struct alignas(8) bh4 { __hip_bfloat16 a, b, c, d; };

__device__ __forceinline__ bh4 pack4(float x, float y, float z, float w) {
    bh4 o { __float2bfloat16(x), __float2bfloat16(y),
            __float2bfloat16(z), __float2bfloat16(w) };
    return o;
}

// ---------------------------------------------------------------- merged cast
__global__ void cast_all(const float* __restrict__ x,
                         const float* __restrict__ w0,
                         const float* __restrict__ w1,
                         const float* __restrict__ w2,
                         __hip_bfloat16* __restrict__ xb,
                         __hip_bfloat16* __restrict__ wb,
                         float* __restrict__ Lbuf) {
    const int bid = blockIdx.x;
    if (bid < 8192) {
        int i = bid * 256 + threadIdx.x;
        float4 v = reinterpret_cast<const float4*>(x)[i];
        reinterpret_cast<bh4*>(xb)[i] = pack4(v.x, v.y, v.z, v.w);
    } else if (bid < 11264) {
        int j = bid - 8192;                       // 0..3071
        int sel = j >> 10;
        const float* src = (sel == 0) ? w0 : (sel == 1) ? w1 : w2;
        int i = (j & 1023) * 256 + threadIdx.x;
        float4 v = reinterpret_cast<const float4*>(src)[i];
        reinterpret_cast<bh4*>(wb + (size_t)sel * 1048576)[i] =
            pack4(v.x, v.y, v.z, v.w);
    } else {
        Lbuf[(bid - 11264) * 256 + threadIdx.x] = 0.f;
    }
}

// ---------------------------------------------------------------- gemm core
__device__ __forceinline__ void load_lds16(const void* g, void* l) {
    __builtin_amdgcn_global_load_lds(
        (const __attribute__((address_space(1))) void*)g,
        (__attribute__((address_space(3))) void*)l, 16, 0, 0);
}

// S-triangle slab tables: half0 rts {12..15, 0..3}, half1 {8..11, 4..7};
// counts are rt+1 (68 tiles per (batch, half) group).
__device__ __constant__ int S_RT0[8] = {12, 13, 14, 15, 0, 1, 2, 3};
__device__ __constant__ int S_RT1[8] = {8, 9, 10, 11, 4, 5, 6, 7};

// C[M,N] = A[M,K]*B[N,K]^T, 128x128 tile, 4 waves, BK=64 (2x 32-k subtiles).
// EPI: 1 = plain bf16 store (QKV) with V cols (ct>=16) redirected transposed
//          into vTout[b][d][t].
//      3 = exp(s/32) masked bf16 + atomic rowsum.
// SWZ: 1 = XCD-slab 1536-block QKV.  3 = XCD-grouped triangle (544 blocks).
template<int EPI, int SWZ>
__global__ __launch_bounds__(256) void gemm_bt(
    const __hip_bfloat16* __restrict__ Abase,
    const __hip_bfloat16* __restrict__ Bbase,
    void* __restrict__ Cbase,
    float* __restrict__ Lbuf,
    __hip_bfloat16* __restrict__ vTout,
    int K, int lda, int ldb, int ldc,
    long batchA, long batchB, long batchC)
{
    int ct, rt, bz;
    if (SWZ == 1) {
        const int bid = blockIdx.x;
        const int xcd = bid & 7;
        const int ii  = bid >> 3;            // 0..191
        rt = (xcd << 3) | (ii & 7);          // 0..63
        ct = ii >> 3;                        // 0..23
        bz = 0;
    } else {                                  // SWZ == 3: XCD-grouped triangle
        const int bid = blockIdx.x;           // 0..543
        const int xcd = bid & 7;
        bz = xcd >> 1;
        const int* rts = (xcd & 1) ? S_RT1 : S_RT0;
        int idx = bid >> 3;                   // 0..67
        int seg = 0;
        while (idx >= rts[seg] + 1) { idx -= rts[seg] + 1; ++seg; }
        rt = rts[seg];
        ct = idx;
    }

    __shared__ short lsA[2][128 * 32];
    __shared__ short lsB[2][128 * 32];

    const int tid  = threadIdx.x;
    const int wave = tid >> 6;
    const int lane = tid & 63;
    const int wr   = (wave >> 1) * 64;
    const int wc   = (wave &  1) * 64;
    const int srow = wave * 32 + (lane >> 2);
    // T2 swizzle: physical slot = logical slot ^ ((row>>1)&3).
    // Staging source col carries the inverse permutation (dest stays linear);
    // all row-base offsets are 0 mod 4 line-pairs so wave terms drop out.
    const int scol = ((lane & 3) ^ ((lane >> 3) & 3)) * 8;
    const int frow = lane & 15;
    const int fk   = (((lane >> 4) ^ ((lane >> 1) & 3)) * 8);

    const short* A = (const short*)Abase + bz * batchA + (long)rt * 128 * lda;
    const short* B = (const short*)Bbase + bz * batchB + (long)ct * 128 * ldb;

    f32x4 acc[4][4] = {};

    for (int k0 = 0; k0 < K; k0 += 64) {
        const short* ga = A + (long)srow * lda + k0 + scol;
        const short* gb = B + (long)srow * ldb + k0 + scol;
        load_lds16(ga,                  &lsA[0][(wave * 32) * 32]);
        load_lds16(ga + 16L * lda,      &lsA[0][(wave * 32 + 16) * 32]);
        load_lds16(ga + 32,             &lsA[1][(wave * 32) * 32]);
        load_lds16(ga + 16L * lda + 32, &lsA[1][(wave * 32 + 16) * 32]);
        load_lds16(gb,                  &lsB[0][(wave * 32) * 32]);
        load_lds16(gb + 16L * ldb,      &lsB[0][(wave * 32 + 16) * 32]);
        load_lds16(gb + 32,             &lsB[1][(wave * 32) * 32]);
        load_lds16(gb + 16L * ldb + 32, &lsB[1][(wave * 32 + 16) * 32]);
        __syncthreads();

        #pragma unroll
        for (int sub = 0; sub < 2; ++sub) {
            bf16x8 af[4], bfr[4];
            #pragma unroll
            for (int m = 0; m < 4; ++m)
                af[m] = *(const bf16x8*)&lsA[sub][(wr + m * 16 + frow) * 32 + fk];
            #pragma unroll
            for (int n = 0; n < 4; ++n)
                bfr[n] = *(const bf16x8*)&lsB[sub][(wc + n * 16 + frow) * 32 + fk];
            #pragma unroll
            for (int m = 0; m < 4; ++m)
                #pragma unroll
                for (int n = 0; n < 4; ++n)
                    acc[m][n] = __builtin_amdgcn_mfma_f32_16x16x32_bf16(
                        af[m], bfr[n], acc[m][n], 0, 0, 0);
        }
        __syncthreads();
    }

    // epilogue: C/D layout col = lane&15, row = (lane>>4)*4 + reg
    const long crow0 = (long)rt * 128 + wr;
    const long ccol0 = (long)ct * 128 + wc;
    const int  orow  = (lane >> 4) * 4;
    const int  ocol  = lane & 15;

    if (EPI == 1) {
        if (SWZ == 1 && ct >= 16) {
            // V columns: store transposed into vT[b][d][t] (d = col-2048).
            // Per (m,n): 4 consecutive t per lane -> one 8B bh4 store.
            #pragma unroll
            for (int m = 0; m < 4; ++m) {
                const long rowb = crow0 + m * 16 + orow;   // multiple of 4
                const long b    = rowb >> 11;
                const long t0   = rowb & 2047;
                #pragma unroll
                for (int n = 0; n < 4; ++n) {
                    const long d = ccol0 + n * 16 + ocol - 2048;
                    bh4 pk = pack4(acc[m][n][0], acc[m][n][1],
                                   acc[m][n][2], acc[m][n][3]);
                    *(bh4*)&vTout[((b << 10) + d) * 2048 + t0] = pk;
                }
            }
        } else {                              // Q/K columns: plain row store
            __hip_bfloat16* C = (__hip_bfloat16*)Cbase;
            #pragma unroll
            for (int m = 0; m < 4; ++m)
                #pragma unroll
                for (int n = 0; n < 4; ++n)
                    #pragma unroll
                    for (int r = 0; r < 4; ++r)
                        C[(crow0 + m * 16 + orow + r) * ldc + ccol0 + n * 16 + ocol] =
                            __float2bfloat16(acc[m][n][r]);
        }
    } else {                                  // EPI == 3: exp + mask + rowsum
        __hip_bfloat16* C = (__hip_bfloat16*)Cbase + bz * batchC;
        float rsum[4][4];
        #pragma unroll
        for (int m = 0; m < 4; ++m)
            #pragma unroll
            for (int r = 0; r < 4; ++r) rsum[m][r] = 0.f;
        #pragma unroll
        for (int m = 0; m < 4; ++m)
            #pragma unroll
            for (int n = 0; n < 4; ++n)
                #pragma unroll
                for (int r = 0; r < 4; ++r) {
                    const long row = crow0 + m * 16 + orow + r;
                    const long col = ccol0 + n * 16 + ocol;
                    float p = (col <= row) ? __expf(acc[m][n][r] * 0.03125f) : 0.f;
                    C[row * ldc + col] = __float2bfloat16(p);
                    rsum[m][r] += p;
                }
        #pragma unroll
        for (int m = 0; m < 4; ++m)
            #pragma unroll
            for (int r = 0; r < 4; ++r) {
                float v = rsum[m][r];
                v += __shfl_xor(v, 1);
                v += __shfl_xor(v, 2);
                v += __shfl_xor(v, 4);
                v += __shfl_xor(v, 8);
                if ((lane & 15) == 0)
                    atomicAdd(&Lbuf[bz * T_SEQ + crow0 + m * 16 + orow + r], v);
            }
    }
}

// ---------------------------------------------------------------- PV split-K
// 768 blocks = 8 XCD-groups x 96. xcd -> (bz = xcd>>1, half = xcd&1).
// idx = bid>>3: p = idx>>3 (0..11), ct = idx&7.
// half0: p<8  -> direct rt=p, full K, scaled -> d_out  (vT t<1024 only)
//        p>=8 -> part0 rt=p (8..11), K tiles [0,8)     -> d_out unscaled
// half1: p<4  -> part0 rt=12+p, K tiles [0,8)          -> d_out unscaled
//        p>=4 -> part1 rt=8+(p-4)=4+p, K [1024,(rt+1)*128) -> tmp1
// Both halves: 68 K-tiles of work. pv_finish combines rows >= 1024.
__global__ __launch_bounds__(256) void pv_split(
    const __hip_bfloat16* __restrict__ P,
    const __hip_bfloat16* __restrict__ Vt,
    float* __restrict__ out,
    float* __restrict__ tmp1,
    const float* __restrict__ Lbuf)
{
    const int bid  = blockIdx.x;             // 0..767
    const int xcd  = bid & 7;
    const int bz   = xcd >> 1;
    const int half = xcd & 1;
    const int idx  = bid >> 3;               // 0..95
    const int p    = idx >> 3;               // 0..11
    const int ct   = idx & 7;

    int rt, k0s, k0e;
    bool scaled = false;
    float* dst;
    if (half == 0) {
        if (p < 8) {
            rt = p; k0s = 0; k0e = (rt + 1) * 128; scaled = true;
            dst = out + (long)bz * 2097152 + (long)rt * 128 * 1024;
        } else {
            rt = p;  // 8..11
            k0s = 0; k0e = 1024;
            dst = out + (long)bz * 2097152 + (long)rt * 128 * 1024;
        }
    } else {
        if (p < 4) {
            rt = 12 + p; k0s = 0; k0e = 1024;
            dst = out + (long)bz * 2097152 + (long)rt * 128 * 1024;
        } else {
            rt = 4 + p;  // 8..15
            k0s = 1024; k0e = (rt + 1) * 128;
            dst = tmp1 + ((long)bz * 1024 + (long)(rt - 8) * 128) * 1024;
        }
    }

    __shared__ short lsA[2][128 * 32];
    __shared__ short lsB[2][128 * 32];

    const int tid  = threadIdx.x;
    const int wave = tid >> 6;
    const int lane = tid & 63;
    const int wr   = (wave >> 1) * 64;
    const int wc   = (wave &  1) * 64;
    const int srow = wave * 32 + (lane >> 2);
    const int scol = ((lane & 3) ^ ((lane >> 3) & 3)) * 8;   // T2 swizzle
    const int frow = lane & 15;
    const int fk   = (((lane >> 4) ^ ((lane >> 1) & 3)) * 8);

    const short* A = (const short*)P  + (long)bz * 4194304 + (long)rt * 128 * 2048;
    const short* B = (const short*)Vt + (long)bz * 2097152 + (long)ct * 128 * 2048;

    f32x4 acc[4][4] = {};

    for (int k0 = k0s; k0 < k0e; k0 += 64) {
        const short* ga = A + (long)srow * 2048 + k0 + scol;
        const short* gb = B + (long)srow * 2048 + k0 + scol;
        load_lds16(ga,                   &lsA[0][(wave * 32) * 32]);
        load_lds16(ga + 16L * 2048,      &lsA[0][(wave * 32 + 16) * 32]);
        load_lds16(ga + 32,              &lsA[1][(wave * 32) * 32]);
        load_lds16(ga + 16L * 2048 + 32, &lsA[1][(wave * 32 + 16) * 32]);
        load_lds16(gb,                   &lsB[0][(wave * 32) * 32]);
        load_lds16(gb + 16L * 2048,      &lsB[0][(wave * 32 + 16) * 32]);
        load_lds16(gb + 32,              &lsB[1][(wave * 32) * 32]);
        load_lds16(gb + 16L * 2048 + 32, &lsB[1][(wave * 32 + 16) * 32]);
        __syncthreads();

        #pragma unroll
        for (int sub = 0; sub < 2; ++sub) {
            bf16x8 af[4], bfr[4];
            #pragma unroll
            for (int m = 0; m < 4; ++m)
                af[m] = *(const bf16x8*)&lsA[sub][(wr + m * 16 + frow) * 32 + fk];
            #pragma unroll
            for (int n = 0; n < 4; ++n)
                bfr[n] = *(const bf16x8*)&lsB[sub][(wc + n * 16 + frow) * 32 + fk];
            #pragma unroll
            for (int m = 0; m < 4; ++m)
                #pragma unroll
                for (int n = 0; n < 4; ++n)
                    acc[m][n] = __builtin_amdgcn_mfma_f32_16x16x32_bf16(
                        af[m], bfr[n], acc[m][n], 0, 0, 0);
        }
        __syncthreads();
    }

    const int orow = (lane >> 4) * 4;
    const int ocol = lane & 15;
    if (scaled) {
        const float* il = Lbuf + bz * T_SEQ + (long)rt * 128;
        #pragma unroll
        for (int m = 0; m < 4; ++m)
            #pragma unroll
            for (int r = 0; r < 4; ++r) {
                const long lrow = wr + m * 16 + orow + r;
                const float s = 1.f / il[lrow];
                #pragma unroll
                for (int n = 0; n < 4; ++n)
                    dst[lrow * 1024 + ct * 128 + wc + n * 16 + ocol] =
                        acc[m][n][r] * s;
            }
    } else {
        #pragma unroll
        for (int m = 0; m < 4; ++m)
            #pragma unroll
            for (int r = 0; r < 4; ++r) {
                const long lrow = wr + m * 16 + orow + r;
                #pragma unroll
                for (int n = 0; n < 4; ++n)
                    dst[lrow * 1024 + ct * 128 + wc + n * 16 + ocol] = acc[m][n][r];
            }
    }
}

// ---------------------------------------------------------------- PV finish
// rows >= 1024 per batch: out = (out + tmp1) / l.
__global__ void pv_finish(float* __restrict__ out,
                          const float* __restrict__ tmp1,
                          const float* __restrict__ Lbuf) {
    const int g = blockIdx.x;                // 0..4095
    const int b = g >> 10;
    const int r = (g & 1023) + 1024;
    const int c = threadIdx.x * 4;
    const float s = 1.f / Lbuf[b * T_SEQ + r];
    float* po = out + (long)b * 2097152 + (long)r * 1024 + c;
    float4 o = *(const float4*)po;
    float4 t = *(const float4*)&tmp1[((long)b * 1024 + (r - 1024)) * 1024 + c];
    o.x = (o.x + t.x) * s; o.y = (o.y + t.y) * s;
    o.z = (o.z + t.z) * s; o.w = (o.w + t.w) * s;
    *(float4*)po = o;
}

// ---------------------------------------------------------------- launch
extern "C" void kernel_launch(void* const* d_in, const int* in_sizes, int n_in,
                              void* d_out, int out_size, void* d_ws, size_t ws_size,
                              hipStream_t stream) {
    const float* x  = (const float*)d_in[0];
    const float* Wq = (const float*)d_in[1];
    const float* Wk = (const float*)d_in[2];
    const float* Wv = (const float*)d_in[3];

    char* ws = (char*)d_ws;
    // workspace (bytes):
    //   xb   @ 0         : 16,777,216   (dead after QKV; tmp1 aliases)
    //   wb   @ 16777216  :  6,291,456
    //   qkv  @ 23068672  : 50,331,648   (Q|K cols used; V cols unwritten)
    //   vT   @ 73400320  : 16,777,216
    //   P    @ 90177536  : 33,554,432
    //   l    @ 123731968 :     32,768
    __hip_bfloat16* xb   = (__hip_bfloat16*)(ws);
    __hip_bfloat16* wb   = (__hip_bfloat16*)(ws + 16777216);
    __hip_bfloat16* qkv  = (__hip_bfloat16*)(ws + 23068672);
    __hip_bfloat16* vT   = (__hip_bfloat16*)(ws + 73400320);
    __hip_bfloat16* P    = (__hip_bfloat16*)(ws + 90177536);
    float*          Lbuf = (float*)        (ws + 123731968);
    float*          tmp1 = (float*)        (ws);              // aliases xb

    // 1) casts + Lbuf zero
    cast_all<<<dim3(11296), 256, 0, stream>>>(x, Wq, Wk, Wv, xb, wb, Lbuf);

    // 2) fused QKV; Q/K rows -> qkv, V -> vT transposed in-epilogue
    gemm_bt<1, 1><<<dim3(1536), 256, 0, stream>>>(
        xb, wb, qkv, nullptr, vT,
        /*K*/1024, /*lda*/1024, /*ldb*/1024, /*ldc*/3072,
        0L, 0L, 0L);

    // 3) P = exp(mask(QK^T)/32) bf16 + atomic rowsums, XCD-grouped triangle
    gemm_bt<3, 3><<<dim3(544), 256, 0, stream>>>(
        qkv, qkv + 1024, P, Lbuf, nullptr,
        /*K*/1024, /*lda*/3072, /*ldb*/3072, /*ldc*/2048,
        /*bA*/6291456L, /*bB*/6291456L, /*bC*/4194304L);

    // 4) O = P @ V ; XCD-grouped split-K, direct rows scaled in-epilogue
    pv_split<<<dim3(768), 256, 0, stream>>>(
        P, vT, (float*)d_out, tmp1, Lbuf);

    // 5) combine + scale split rows
    pv_finish<<<dim3(4096), 256, 0, stream>>>((float*)d_out, tmp1, Lbuf);
}

// Round 4
// 235.772 us; speedup vs baseline: 1.0592x; 1.0248x over previous
//
#include <hip/hip_runtime.h>
#include <hip/hip_bf16.h>

// B=4, T=2048, C=1024 single-head causal attention, fp32 in/out.
// R12: QKV GEMM moved to a fat-wave core: block 256x128, 4 waves in 2x2,
// wave tile 128x64 (acc[8][4]) -> 12 ds_read_b128 per 32 MFMA (-25% LDS
// traffic per unit work vs 64x64 wave tiles). Proven 2-phase sync, T2
// swizzle (row bases all 0 mod 16 so lane formulas unchanged), linear
// gload_lds dest + inverse-swizzled source. S-gemm / pv_split unchanged.

typedef short bf16x8 __attribute__((ext_vector_type(8)));
typedef float f32x4  __attribute__((ext_vector_type(4)));

#define T_SEQ 2048
#define EMB   1024
#define NBAT  4

struct alignas(8) bh4 { __hip_bfloat16 a, b, c, d; };

__device__ __forceinline__ bh4 pack4(float x, float y, float z, float w) {
    bh4 o { __float2bfloat16(x), __float2bfloat16(y),
            __float2bfloat16(z), __float2bfloat16(w) };
    return o;
}

// ---------------------------------------------------------------- merged cast
__global__ void cast_all(const float* __restrict__ x,
                         const float* __restrict__ w0,
                         const float* __restrict__ w1,
                         const float* __restrict__ w2,
                         __hip_bfloat16* __restrict__ xb,
                         __hip_bfloat16* __restrict__ wb,
                         float* __restrict__ Lbuf) {
    const int bid = blockIdx.x;
    if (bid < 8192) {
        int i = bid * 256 + threadIdx.x;
        float4 v = reinterpret_cast<const float4*>(x)[i];
        reinterpret_cast<bh4*>(xb)[i] = pack4(v.x, v.y, v.z, v.w);
    } else if (bid < 11264) {
        int j = bid - 8192;                       // 0..3071
        int sel = j >> 10;
        const float* src = (sel == 0) ? w0 : (sel == 1) ? w1 : w2;
        int i = (j & 1023) * 256 + threadIdx.x;
        float4 v = reinterpret_cast<const float4*>(src)[i];
        reinterpret_cast<bh4*>(wb + (size_t)sel * 1048576)[i] =
            pack4(v.x, v.y, v.z, v.w);
    } else {
        Lbuf[(bid - 11264) * 256 + threadIdx.x] = 0.f;
    }
}

// ---------------------------------------------------------------- helpers
__device__ __forceinline__ void load_lds16(const void* g, void* l) {
    __builtin_amdgcn_global_load_lds(
        (const __attribute__((address_space(1))) void*)g,
        (__attribute__((address_space(3))) void*)l, 16, 0, 0);
}

// ================================================================ QKV core
// C = A[8192,1024] * B[3072,1024]^T. Block 256x128, 4 waves, wave 128x64.
// Q/K cols -> qkv rows; V cols (ct>=16) -> vT[b][d][t] transposed.
__global__ __launch_bounds__(256, 2) void qkv_gemm(
    const __hip_bfloat16* __restrict__ Abase,
    const __hip_bfloat16* __restrict__ Bbase,
    __hip_bfloat16* __restrict__ qkvOut,
    __hip_bfloat16* __restrict__ vTout)
{
    const int bid = blockIdx.x;               // 0..767 (768 = 8 XCD x 96)
    const int xcd = bid & 7;
    const int ii  = bid >> 3;                 // 0..95
    const int rt  = (xcd << 2) | (ii & 3);    // 0..31 (rows of 256)
    const int ct  = ii >> 2;                  // 0..23 (cols of 128)

    __shared__ short lsA[2][256 * 32];        // 32 KiB
    __shared__ short lsB[2][128 * 32];        // 16 KiB

    const int tid  = threadIdx.x;
    const int wave = tid >> 6;
    const int lane = tid & 63;
    const int wr   = (wave >> 1) * 128;       // wave row base in tile
    const int wc   = (wave &  1) * 64;        // wave col base in tile
    const int sr   = lane >> 2;               // staging row 0..15
    // T2 swizzle (identical lane formulas to the proven 128x128 core;
    // all row-base offsets here are 0 mod 16 so they drop out of the XOR):
    const int scol = ((lane & 3) ^ ((lane >> 3) & 3)) * 8;
    const int frow = lane & 15;
    const int fk   = ((lane >> 4) ^ ((lane >> 1) & 3)) * 8;

    const short* A = (const short*)Abase + (long)rt * 256 * 1024;
    const short* B = (const short*)Bbase + (long)ct * 128 * 1024;

    f32x4 acc[8][4] = {};

    for (int k0 = 0; k0 < 1024; k0 += 64) {
        const short* ga = A + (long)(wave * 64 + sr) * 1024 + k0 + scol;
        const short* gb = B + (long)(wave * 32 + sr) * 1024 + k0 + scol;
        #pragma unroll
        for (int i = 0; i < 4; ++i) {
            load_lds16(ga + (long)i * 16384,      &lsA[0][(wave * 64 + i * 16) * 32]);
            load_lds16(ga + (long)i * 16384 + 32, &lsA[1][(wave * 64 + i * 16) * 32]);
        }
        #pragma unroll
        for (int i = 0; i < 2; ++i) {
            load_lds16(gb + (long)i * 16384,      &lsB[0][(wave * 32 + i * 16) * 32]);
            load_lds16(gb + (long)i * 16384 + 32, &lsB[1][(wave * 32 + i * 16) * 32]);
        }
        __syncthreads();

        #pragma unroll
        for (int sub = 0; sub < 2; ++sub) {
            bf16x8 af[8], bfr[4];
            #pragma unroll
            for (int m = 0; m < 8; ++m)
                af[m] = *(const bf16x8*)&lsA[sub][(wr + m * 16 + frow) * 32 + fk];
            #pragma unroll
            for (int n = 0; n < 4; ++n)
                bfr[n] = *(const bf16x8*)&lsB[sub][(wc + n * 16 + frow) * 32 + fk];
            #pragma unroll
            for (int m = 0; m < 8; ++m)
                #pragma unroll
                for (int n = 0; n < 4; ++n)
                    acc[m][n] = __builtin_amdgcn_mfma_f32_16x16x32_bf16(
                        af[m], bfr[n], acc[m][n], 0, 0, 0);
        }
        __syncthreads();
    }

    // epilogue: C/D layout col = lane&15, row = (lane>>4)*4 + reg
    const long crow0 = (long)rt * 256 + wr;
    const long ccol0 = (long)ct * 128 + wc;
    const int  orow  = (lane >> 4) * 4;
    const int  ocol  = lane & 15;

    if (ct >= 16) {
        // V columns: store transposed into vT[b][d][t] (d = col-2048).
        #pragma unroll
        for (int m = 0; m < 8; ++m) {
            const long rowb = crow0 + m * 16 + orow;   // multiple of 4
            const long b    = rowb >> 11;
            const long t0   = rowb & 2047;
            #pragma unroll
            for (int n = 0; n < 4; ++n) {
                const long d = ccol0 + n * 16 + ocol - 2048;
                bh4 pk = pack4(acc[m][n][0], acc[m][n][1],
                               acc[m][n][2], acc[m][n][3]);
                *(bh4*)&vTout[((b << 10) + d) * 2048 + t0] = pk;
            }
        }
    } else {                                  // Q/K columns: plain row store
        #pragma unroll
        for (int m = 0; m < 8; ++m)
            #pragma unroll
            for (int n = 0; n < 4; ++n)
                #pragma unroll
                for (int r = 0; r < 4; ++r)
                    qkvOut[(crow0 + m * 16 + orow + r) * 3072 +
                           ccol0 + n * 16 + ocol] =
                        __float2bfloat16(acc[m][n][r]);
    }
}

// ---------------------------------------------------------------- gemm core
// S-triangle slab tables: half0 rts {12..15, 0..3}, half1 {8..11, 4..7};
// counts are rt+1 (68 tiles per (batch, half) group).
__device__ __constant__ int S_RT0[8] = {12, 13, 14, 15, 0, 1, 2, 3};
__device__ __constant__ int S_RT1[8] = {8, 9, 10, 11, 4, 5, 6, 7};

// C[M,N] = A[M,K]*B[N,K]^T, 128x128 tile, 4 waves, BK=64 (2x 32-k subtiles).
// EPI 3 = exp(s/32) masked bf16 + atomic rowsum; SWZ 3 = XCD triangle.
template<int EPI, int SWZ>
__global__ __launch_bounds__(256) void gemm_bt(
    const __hip_bfloat16* __restrict__ Abase,
    const __hip_bfloat16* __restrict__ Bbase,
    void* __restrict__ Cbase,
    float* __restrict__ Lbuf,
    int K, int lda, int ldb, int ldc,
    long batchA, long batchB, long batchC)
{
    int ct, rt, bz;
    {                                         // SWZ == 3: XCD-grouped triangle
        const int bid = blockIdx.x;           // 0..543
        const int xcd = bid & 7;
        bz = xcd >> 1;
        const int* rts = (xcd & 1) ? S_RT1 : S_RT0;
        int idx = bid >> 3;                   // 0..67
        int seg = 0;
        while (idx >= rts[seg] + 1) { idx -= rts[seg] + 1; ++seg; }
        rt = rts[seg];
        ct = idx;
    }

    __shared__ short lsA[2][128 * 32];
    __shared__ short lsB[2][128 * 32];

    const int tid  = threadIdx.x;
    const int wave = tid >> 6;
    const int lane = tid & 63;
    const int wr   = (wave >> 1) * 64;
    const int wc   = (wave &  1) * 64;
    const int srow = wave * 32 + (lane >> 2);
    const int scol = ((lane & 3) ^ ((lane >> 3) & 3)) * 8;   // T2 swizzle
    const int frow = lane & 15;
    const int fk   = ((lane >> 4) ^ ((lane >> 1) & 3)) * 8;

    const short* A = (const short*)Abase + bz * batchA + (long)rt * 128 * lda;
    const short* B = (const short*)Bbase + bz * batchB + (long)ct * 128 * ldb;

    f32x4 acc[4][4] = {};

    for (int k0 = 0; k0 < K; k0 += 64) {
        const short* ga = A + (long)srow * lda + k0 + scol;
        const short* gb = B + (long)srow * ldb + k0 + scol;
        load_lds16(ga,                  &lsA[0][(wave * 32) * 32]);
        load_lds16(ga + 16L * lda,      &lsA[0][(wave * 32 + 16) * 32]);
        load_lds16(ga + 32,             &lsA[1][(wave * 32) * 32]);
        load_lds16(ga + 16L * lda + 32, &lsA[1][(wave * 32 + 16) * 32]);
        load_lds16(gb,                  &lsB[0][(wave * 32) * 32]);
        load_lds16(gb + 16L * ldb,      &lsB[0][(wave * 32 + 16) * 32]);
        load_lds16(gb + 32,             &lsB[1][(wave * 32) * 32]);
        load_lds16(gb + 16L * ldb + 32, &lsB[1][(wave * 32 + 16) * 32]);
        __syncthreads();

        #pragma unroll
        for (int sub = 0; sub < 2; ++sub) {
            bf16x8 af[4], bfr[4];
            #pragma unroll
            for (int m = 0; m < 4; ++m)
                af[m] = *(const bf16x8*)&lsA[sub][(wr + m * 16 + frow) * 32 + fk];
            #pragma unroll
            for (int n = 0; n < 4; ++n)
                bfr[n] = *(const bf16x8*)&lsB[sub][(wc + n * 16 + frow) * 32 + fk];
            #pragma unroll
            for (int m = 0; m < 4; ++m)
                #pragma unroll
                for (int n = 0; n < 4; ++n)
                    acc[m][n] = __builtin_amdgcn_mfma_f32_16x16x32_bf16(
                        af[m], bfr[n], acc[m][n], 0, 0, 0);
        }
        __syncthreads();
    }

    // epilogue: C/D layout col = lane&15, row = (lane>>4)*4 + reg
    const long crow0 = (long)rt * 128 + wr;
    const long ccol0 = (long)ct * 128 + wc;
    const int  orow  = (lane >> 4) * 4;
    const int  ocol  = lane & 15;

    {                                         // EPI == 3: exp + mask + rowsum
        __hip_bfloat16* C = (__hip_bfloat16*)Cbase + bz * batchC;
        float rsum[4][4];
        #pragma unroll
        for (int m = 0; m < 4; ++m)
            #pragma unroll
            for (int r = 0; r < 4; ++r) rsum[m][r] = 0.f;
        #pragma unroll
        for (int m = 0; m < 4; ++m)
            #pragma unroll
            for (int n = 0; n < 4; ++n)
                #pragma unroll
                for (int r = 0; r < 4; ++r) {
                    const long row = crow0 + m * 16 + orow + r;
                    const long col = ccol0 + n * 16 + ocol;
                    float p = (col <= row) ? __expf(acc[m][n][r] * 0.03125f) : 0.f;
                    C[row * ldc + col] = __float2bfloat16(p);
                    rsum[m][r] += p;
                }
        #pragma unroll
        for (int m = 0; m < 4; ++m)
            #pragma unroll
            for (int r = 0; r < 4; ++r) {
                float v = rsum[m][r];
                v += __shfl_xor(v, 1);
                v += __shfl_xor(v, 2);
                v += __shfl_xor(v, 4);
                v += __shfl_xor(v, 8);
                if ((lane & 15) == 0)
                    atomicAdd(&Lbuf[bz * T_SEQ + crow0 + m * 16 + orow + r], v);
            }
    }
}

// ---------------------------------------------------------------- PV split-K
// 768 blocks = 8 XCD-groups x 96. xcd -> (bz = xcd>>1, half = xcd&1).
// idx = bid>>3: p = idx>>3 (0..11), ct = idx&7.
// half0: p<8  -> direct rt=p, full K, scaled -> d_out  (vT t<1024 only)
//        p>=8 -> part0 rt=p (8..11), K tiles [0,8)     -> d_out unscaled
// half1: p<4  -> part0 rt=12+p, K tiles [0,8)          -> d_out unscaled
//        p>=4 -> part1 rt=8+(p-4)=4+p, K [1024,(rt+1)*128) -> tmp1
// Both halves: 68 K-tiles of work. pv_finish combines rows >= 1024.
__global__ __launch_bounds__(256) void pv_split(
    const __hip_bfloat16* __restrict__ P,
    const __hip_bfloat16* __restrict__ Vt,
    float* __restrict__ out,
    float* __restrict__ tmp1,
    const float* __restrict__ Lbuf)
{
    const int bid  = blockIdx.x;             // 0..767
    const int xcd  = bid & 7;
    const int bz   = xcd >> 1;
    const int half = xcd & 1;
    const int idx  = bid >> 3;               // 0..95
    const int p    = idx >> 3;               // 0..11
    const int ct   = idx & 7;

    int rt, k0s, k0e;
    bool scaled = false;
    float* dst;
    if (half == 0) {
        if (p < 8) {
            rt = p; k0s = 0; k0e = (rt + 1) * 128; scaled = true;
            dst = out + (long)bz * 2097152 + (long)rt * 128 * 1024;
        } else {
            rt = p;  // 8..11
            k0s = 0; k0e = 1024;
            dst = out + (long)bz * 2097152 + (long)rt * 128 * 1024;
        }
    } else {
        if (p < 4) {
            rt = 12 + p; k0s = 0; k0e = 1024;
            dst = out + (long)bz * 2097152 + (long)rt * 128 * 1024;
        } else {
            rt = 4 + p;  // 8..15
            k0s = 1024; k0e = (rt + 1) * 128;
            dst = tmp1 + ((long)bz * 1024 + (long)(rt - 8) * 128) * 1024;
        }
    }

    __shared__ short lsA[2][128 * 32];
    __shared__ short lsB[2][128 * 32];

    const int tid  = threadIdx.x;
    const int wave = tid >> 6;
    const int lane = tid & 63;
    const int wr   = (wave >> 1) * 64;
    const int wc   = (wave &  1) * 64;
    const int srow = wave * 32 + (lane >> 2);
    const int scol = ((lane & 3) ^ ((lane >> 3) & 3)) * 8;   // T2 swizzle
    const int frow = lane & 15;
    const int fk   = ((lane >> 4) ^ ((lane >> 1) & 3)) * 8;

    const short* A = (const short*)P  + (long)bz * 4194304 + (long)rt * 128 * 2048;
    const short* B = (const short*)Vt + (long)bz * 2097152 + (long)ct * 128 * 2048;

    f32x4 acc[4][4] = {};

    for (int k0 = k0s; k0 < k0e; k0 += 64) {
        const short* ga = A + (long)srow * 2048 + k0 + scol;
        const short* gb = B + (long)srow * 2048 + k0 + scol;
        load_lds16(ga,                   &lsA[0][(wave * 32) * 32]);
        load_lds16(ga + 16L * 2048,      &lsA[0][(wave * 32 + 16) * 32]);
        load_lds16(ga + 32,              &lsA[1][(wave * 32) * 32]);
        load_lds16(ga + 16L * 2048 + 32, &lsA[1][(wave * 32 + 16) * 32]);
        load_lds16(gb,                   &lsB[0][(wave * 32) * 32]);
        load_lds16(gb + 16L * 2048,      &lsB[0][(wave * 32 + 16) * 32]);
        load_lds16(gb + 32,              &lsB[1][(wave * 32) * 32]);
        load_lds16(gb + 16L * 2048 + 32, &lsB[1][(wave * 32 + 16) * 32]);
        __syncthreads();

        #pragma unroll
        for (int sub = 0; sub < 2; ++sub) {
            bf16x8 af[4], bfr[4];
            #pragma unroll
            for (int m = 0; m < 4; ++m)
                af[m] = *(const bf16x8*)&lsA[sub][(wr + m * 16 + frow) * 32 + fk];
            #pragma unroll
            for (int n = 0; n < 4; ++n)
                bfr[n] = *(const bf16x8*)&lsB[sub][(wc + n * 16 + frow) * 32 + fk];
            #pragma unroll
            for (int m = 0; m < 4; ++m)
                #pragma unroll
                for (int n = 0; n < 4; ++n)
                    acc[m][n] = __builtin_amdgcn_mfma_f32_16x16x32_bf16(
                        af[m], bfr[n], acc[m][n], 0, 0, 0);
        }
        __syncthreads();
    }

    const int orow = (lane >> 4) * 4;
    const int ocol = lane & 15;
    if (scaled) {
        const float* il = Lbuf + bz * T_SEQ + (long)rt * 128;
        #pragma unroll
        for (int m = 0; m < 4; ++m)
            #pragma unroll
            for (int r = 0; r < 4; ++r) {
                const long lrow = wr + m * 16 + orow + r;
                const float s = 1.f / il[lrow];
                #pragma unroll
                for (int n = 0; n < 4; ++n)
                    dst[lrow * 1024 + ct * 128 + wc + n * 16 + ocol] =
                        acc[m][n][r] * s;
            }
    } else {
        #pragma unroll
        for (int m = 0; m < 4; ++m)
            #pragma unroll
            for (int r = 0; r < 4; ++r) {
                const long lrow = wr + m * 16 + orow + r;
                #pragma unroll
                for (int n = 0; n < 4; ++n)
                    dst[lrow * 1024 + ct * 128 + wc + n * 16 + ocol] = acc[m][n][r];
            }
    }
}

// ---------------------------------------------------------------- PV finish
// rows >= 1024 per batch: out = (out + tmp1) / l.
__global__ void pv_finish(float* __restrict__ out,
                          const float* __restrict__ tmp1,
                          const float* __restrict__ Lbuf) {
    const int g = blockIdx.x;                // 0..4095
    const int b = g >> 10;
    const int r = (g & 1023) + 1024;
    const int c = threadIdx.x * 4;
    const float s = 1.f / Lbuf[b * T_SEQ + r];
    float* po = out + (long)b * 2097152 + (long)r * 1024 + c;
    float4 o = *(const float4*)po;
    float4 t = *(const float4*)&tmp1[((long)b * 1024 + (r - 1024)) * 1024 + c];
    o.x = (o.x + t.x) * s; o.y = (o.y + t.y) * s;
    o.z = (o.z + t.z) * s; o.w = (o.w + t.w) * s;
    *(float4*)po = o;
}

// ---------------------------------------------------------------- launch
extern "C" void kernel_launch(void* const* d_in, const int* in_sizes, int n_in,
                              void* d_out, int out_size, void* d_ws, size_t ws_size,
                              hipStream_t stream) {
    const float* x  = (const float*)d_in[0];
    const float* Wq = (const float*)d_in[1];
    const float* Wk = (const float*)d_in[2];
    const float* Wv = (const float*)d_in[3];

    char* ws = (char*)d_ws;
    // workspace (bytes):
    //   xb   @ 0         : 16,777,216   (dead after QKV; tmp1 aliases)
    //   wb   @ 16777216  :  6,291,456
    //   qkv  @ 23068672  : 50,331,648   (Q|K cols used; V cols unwritten)
    //   vT   @ 73400320  : 16,777,216
    //   P    @ 90177536  : 33,554,432
    //   l    @ 123731968 :     32,768
    __hip_bfloat16* xb   = (__hip_bfloat16*)(ws);
    __hip_bfloat16* wb   = (__hip_bfloat16*)(ws + 16777216);
    __hip_bfloat16* qkv  = (__hip_bfloat16*)(ws + 23068672);
    __hip_bfloat16* vT   = (__hip_bfloat16*)(ws + 73400320);
    __hip_bfloat16* P    = (__hip_bfloat16*)(ws + 90177536);
    float*          Lbuf = (float*)        (ws + 123731968);
    float*          tmp1 = (float*)        (ws);              // aliases xb

    // 1) casts + Lbuf zero
    cast_all<<<dim3(11296), 256, 0, stream>>>(x, Wq, Wk, Wv, xb, wb, Lbuf);

    // 2) fused QKV; fat-wave 256x128 core. Q/K -> qkv, V -> vT transposed
    qkv_gemm<<<dim3(768), 256, 0, stream>>>(xb, wb, qkv, vT);

    // 3) P = exp(mask(QK^T)/32) bf16 + atomic rowsums, XCD-grouped triangle
    gemm_bt<3, 3><<<dim3(544), 256, 0, stream>>>(
        qkv, qkv + 1024, P, Lbuf,
        /*K*/1024, /*lda*/3072, /*ldb*/3072, /*ldc*/2048,
        /*bA*/6291456L, /*bB*/6291456L, /*bC*/4194304L);

    // 4) O = P @ V ; XCD-grouped split-K, direct rows scaled in-epilogue
    pv_split<<<dim3(768), 256, 0, stream>>>(
        P, vT, (float*)d_out, tmp1, Lbuf);

    // 5) combine + scale split rows
    pv_finish<<<dim3(4096), 256, 0, stream>>>((float*)d_out, tmp1, Lbuf);
}

// Round 6
// 222.961 us; speedup vs baseline: 1.1200x; 1.0575x over previous
//
#include <hip/hip_runtime.h>
#include <hip/hip_bf16.h>

// B=4, T=2048, C=1024 single-head causal attention, fp32 in/out.
// R13 (resubmit; R5 was an infra failure, container never ran):
// S-GEMM ported to the fat-wave core (256x128 tile, 4 waves, wave
// 128x64, acc[8][4]) — 288 blocks (8 XCD x 36), triangle decoded from
// j in [rt(rt+1),(rt+1)(rt+2)). Epilogue: per-(m,r) scalar rowsum + exp
// mask + atomicAdd (low VGPR). qkv_gemm / pv_split / pv_finish frozen.

typedef short bf16x8 __attribute__((ext_vector_type(8)));
typedef float f32x4  __attribute__((ext_vector_type(4)));

#define T_SEQ 2048
#define EMB   1024
#define NBAT  4

struct alignas(8) bh4 { __hip_bfloat16 a, b, c, d; };

__device__ __forceinline__ bh4 pack4(float x, float y, float z, float w) {
    bh4 o { __float2bfloat16(x), __float2bfloat16(y),
            __float2bfloat16(z), __float2bfloat16(w) };
    return o;
}

// ---------------------------------------------------------------- merged cast
__global__ void cast_all(const float* __restrict__ x,
                         const float* __restrict__ w0,
                         const float* __restrict__ w1,
                         const float* __restrict__ w2,
                         __hip_bfloat16* __restrict__ xb,
                         __hip_bfloat16* __restrict__ wb,
                         float* __restrict__ Lbuf) {
    const int bid = blockIdx.x;
    if (bid < 8192) {
        int i = bid * 256 + threadIdx.x;
        float4 v = reinterpret_cast<const float4*>(x)[i];
        reinterpret_cast<bh4*>(xb)[i] = pack4(v.x, v.y, v.z, v.w);
    } else if (bid < 11264) {
        int j = bid - 8192;                       // 0..3071
        int sel = j >> 10;
        const float* src = (sel == 0) ? w0 : (sel == 1) ? w1 : w2;
        int i = (j & 1023) * 256 + threadIdx.x;
        float4 v = reinterpret_cast<const float4*>(src)[i];
        reinterpret_cast<bh4*>(wb + (size_t)sel * 1048576)[i] =
            pack4(v.x, v.y, v.z, v.w);
    } else {
        Lbuf[(bid - 11264) * 256 + threadIdx.x] = 0.f;
    }
}

// ---------------------------------------------------------------- helpers
__device__ __forceinline__ void load_lds16(const void* g, void* l) {
    __builtin_amdgcn_global_load_lds(
        (const __attribute__((address_space(1))) void*)g,
        (__attribute__((address_space(3))) void*)l, 16, 0, 0);
}

// ================================================================ QKV core
// C = A[8192,1024] * B[3072,1024]^T. Block 256x128, 4 waves, wave 128x64.
// Q/K cols -> qkv rows; V cols (ct>=16) -> vT[b][d][t] transposed.
__global__ __launch_bounds__(256, 2) void qkv_gemm(
    const __hip_bfloat16* __restrict__ Abase,
    const __hip_bfloat16* __restrict__ Bbase,
    __hip_bfloat16* __restrict__ qkvOut,
    __hip_bfloat16* __restrict__ vTout)
{
    const int bid = blockIdx.x;               // 0..767 (768 = 8 XCD x 96)
    const int xcd = bid & 7;
    const int ii  = bid >> 3;                 // 0..95
    const int rt  = (xcd << 2) | (ii & 3);    // 0..31 (rows of 256)
    const int ct  = ii >> 2;                  // 0..23 (cols of 128)

    __shared__ short lsA[2][256 * 32];        // 32 KiB
    __shared__ short lsB[2][128 * 32];        // 16 KiB

    const int tid  = threadIdx.x;
    const int wave = tid >> 6;
    const int lane = tid & 63;
    const int wr   = (wave >> 1) * 128;       // wave row base in tile
    const int wc   = (wave &  1) * 64;        // wave col base in tile
    const int sr   = lane >> 2;               // staging row 0..15
    // T2 swizzle (all row-base offsets are 0 mod 16 so they drop out):
    const int scol = ((lane & 3) ^ ((lane >> 3) & 3)) * 8;
    const int frow = lane & 15;
    const int fk   = ((lane >> 4) ^ ((lane >> 1) & 3)) * 8;

    const short* A = (const short*)Abase + (long)rt * 256 * 1024;
    const short* B = (const short*)Bbase + (long)ct * 128 * 1024;

    f32x4 acc[8][4] = {};

    for (int k0 = 0; k0 < 1024; k0 += 64) {
        const short* ga = A + (long)(wave * 64 + sr) * 1024 + k0 + scol;
        const short* gb = B + (long)(wave * 32 + sr) * 1024 + k0 + scol;
        #pragma unroll
        for (int i = 0; i < 4; ++i) {
            load_lds16(ga + (long)i * 16384,      &lsA[0][(wave * 64 + i * 16) * 32]);
            load_lds16(ga + (long)i * 16384 + 32, &lsA[1][(wave * 64 + i * 16) * 32]);
        }
        #pragma unroll
        for (int i = 0; i < 2; ++i) {
            load_lds16(gb + (long)i * 16384,      &lsB[0][(wave * 32 + i * 16) * 32]);
            load_lds16(gb + (long)i * 16384 + 32, &lsB[1][(wave * 32 + i * 16) * 32]);
        }
        __syncthreads();

        #pragma unroll
        for (int sub = 0; sub < 2; ++sub) {
            bf16x8 af[8], bfr[4];
            #pragma unroll
            for (int m = 0; m < 8; ++m)
                af[m] = *(const bf16x8*)&lsA[sub][(wr + m * 16 + frow) * 32 + fk];
            #pragma unroll
            for (int n = 0; n < 4; ++n)
                bfr[n] = *(const bf16x8*)&lsB[sub][(wc + n * 16 + frow) * 32 + fk];
            #pragma unroll
            for (int m = 0; m < 8; ++m)
                #pragma unroll
                for (int n = 0; n < 4; ++n)
                    acc[m][n] = __builtin_amdgcn_mfma_f32_16x16x32_bf16(
                        af[m], bfr[n], acc[m][n], 0, 0, 0);
        }
        __syncthreads();
    }

    // epilogue: C/D layout col = lane&15, row = (lane>>4)*4 + reg
    const long crow0 = (long)rt * 256 + wr;
    const long ccol0 = (long)ct * 128 + wc;
    const int  orow  = (lane >> 4) * 4;
    const int  ocol  = lane & 15;

    if (ct >= 16) {
        // V columns: store transposed into vT[b][d][t] (d = col-2048).
        #pragma unroll
        for (int m = 0; m < 8; ++m) {
            const long rowb = crow0 + m * 16 + orow;   // multiple of 4
            const long b    = rowb >> 11;
            const long t0   = rowb & 2047;
            #pragma unroll
            for (int n = 0; n < 4; ++n) {
                const long d = ccol0 + n * 16 + ocol - 2048;
                bh4 pk = pack4(acc[m][n][0], acc[m][n][1],
                               acc[m][n][2], acc[m][n][3]);
                *(bh4*)&vTout[((b << 10) + d) * 2048 + t0] = pk;
            }
        }
    } else {                                  // Q/K columns: plain row store
        #pragma unroll
        for (int m = 0; m < 8; ++m)
            #pragma unroll
            for (int n = 0; n < 4; ++n)
                #pragma unroll
                for (int r = 0; r < 4; ++r)
                    qkvOut[(crow0 + m * 16 + orow + r) * 3072 +
                           ccol0 + n * 16 + ocol] =
                        __float2bfloat16(acc[m][n][r]);
    }
}

// ================================================================ S core
// P = exp(mask(Q K^T)/32) bf16 + atomic rowsums. Fat-wave 256x128 tiles.
// 288 blocks = 8 XCD x 36. xcd -> bz = xcd>>1, half = xcd&1.
// j = half*36 + (bid>>3) in 0..71; tile j of batch bz's triangle:
// rt s.t. j in [rt(rt+1), (rt+1)(rt+2)), ct = j - rt(rt+1)  (ct <= 2rt+1).
__global__ __launch_bounds__(256, 2) void s_gemm(
    const __hip_bfloat16* __restrict__ QKV,
    __hip_bfloat16* __restrict__ P,
    float* __restrict__ Lbuf)
{
    const int bid  = blockIdx.x;              // 0..287
    const int xcd  = bid & 7;
    const int bz   = xcd >> 1;
    int j = (xcd & 1) * 36 + (bid >> 3);      // 0..71
    int rt = 0;
    while (j >= (rt + 1) * (rt + 2)) ++rt;    // <= 7 iterations
    const int ct = j - rt * (rt + 1);

    __shared__ short lsA[2][256 * 32];        // 32 KiB
    __shared__ short lsB[2][128 * 32];        // 16 KiB

    const int tid  = threadIdx.x;
    const int wave = tid >> 6;
    const int lane = tid & 63;
    const int wr   = (wave >> 1) * 128;
    const int wc   = (wave &  1) * 64;
    const int sr   = lane >> 2;
    const int scol = ((lane & 3) ^ ((lane >> 3) & 3)) * 8;   // T2 swizzle
    const int frow = lane & 15;
    const int fk   = ((lane >> 4) ^ ((lane >> 1) & 3)) * 8;

    const short* A = (const short*)QKV + (long)bz * 6291456
                   + (long)rt * 256 * 3072;            // Q rows
    const short* B = (const short*)QKV + (long)bz * 6291456 + 1024
                   + (long)ct * 128 * 3072;            // K rows

    f32x4 acc[8][4] = {};

    for (int k0 = 0; k0 < 1024; k0 += 64) {
        const short* ga = A + (long)(wave * 64 + sr) * 3072 + k0 + scol;
        const short* gb = B + (long)(wave * 32 + sr) * 3072 + k0 + scol;
        #pragma unroll
        for (int i = 0; i < 4; ++i) {
            load_lds16(ga + (long)i * 49152,      &lsA[0][(wave * 64 + i * 16) * 32]);
            load_lds16(ga + (long)i * 49152 + 32, &lsA[1][(wave * 64 + i * 16) * 32]);
        }
        #pragma unroll
        for (int i = 0; i < 2; ++i) {
            load_lds16(gb + (long)i * 49152,      &lsB[0][(wave * 32 + i * 16) * 32]);
            load_lds16(gb + (long)i * 49152 + 32, &lsB[1][(wave * 32 + i * 16) * 32]);
        }
        __syncthreads();

        #pragma unroll
        for (int sub = 0; sub < 2; ++sub) {
            bf16x8 af[8], bfr[4];
            #pragma unroll
            for (int m = 0; m < 8; ++m)
                af[m] = *(const bf16x8*)&lsA[sub][(wr + m * 16 + frow) * 32 + fk];
            #pragma unroll
            for (int n = 0; n < 4; ++n)
                bfr[n] = *(const bf16x8*)&lsB[sub][(wc + n * 16 + frow) * 32 + fk];
            #pragma unroll
            for (int m = 0; m < 8; ++m)
                #pragma unroll
                for (int n = 0; n < 4; ++n)
                    acc[m][n] = __builtin_amdgcn_mfma_f32_16x16x32_bf16(
                        af[m], bfr[n], acc[m][n], 0, 0, 0);
        }
        __syncthreads();
    }

    // epilogue: exp(s/32) masked + per-row sums (scalar rowsum per (m,r))
    const long crow0 = (long)rt * 256 + wr;
    const long ccol0 = (long)ct * 128 + wc;
    const int  orow  = (lane >> 4) * 4;
    const int  ocol  = lane & 15;
    __hip_bfloat16* C = P + (long)bz * 4194304;

    #pragma unroll
    for (int m = 0; m < 8; ++m)
        #pragma unroll
        for (int r = 0; r < 4; ++r) {
            const long row = crow0 + m * 16 + orow + r;
            float sum = 0.f;
            #pragma unroll
            for (int n = 0; n < 4; ++n) {
                const long col = ccol0 + n * 16 + ocol;
                float p = (col <= row) ? __expf(acc[m][n][r] * 0.03125f) : 0.f;
                C[row * 2048 + col] = __float2bfloat16(p);
                sum += p;
            }
            sum += __shfl_xor(sum, 1);
            sum += __shfl_xor(sum, 2);
            sum += __shfl_xor(sum, 4);
            sum += __shfl_xor(sum, 8);
            if ((lane & 15) == 0)
                atomicAdd(&Lbuf[bz * T_SEQ + row], sum);
        }
}

// ---------------------------------------------------------------- PV split-K
// 768 blocks = 8 XCD-groups x 96. xcd -> (bz = xcd>>1, half = xcd&1).
// idx = bid>>3: p = idx>>3 (0..11), ct = idx&7.
// half0: p<8  -> direct rt=p, full K, scaled -> d_out  (vT t<1024 only)
//        p>=8 -> part0 rt=p (8..11), K tiles [0,8)     -> d_out unscaled
// half1: p<4  -> part0 rt=12+p, K tiles [0,8)          -> d_out unscaled
//        p>=4 -> part1 rt=8+(p-4)=4+p, K [1024,(rt+1)*128) -> tmp1
// Both halves: 68 K-tiles of work. pv_finish combines rows >= 1024.
__global__ __launch_bounds__(256) void pv_split(
    const __hip_bfloat16* __restrict__ P,
    const __hip_bfloat16* __restrict__ Vt,
    float* __restrict__ out,
    float* __restrict__ tmp1,
    const float* __restrict__ Lbuf)
{
    const int bid  = blockIdx.x;             // 0..767
    const int xcd  = bid & 7;
    const int bz   = xcd >> 1;
    const int half = xcd & 1;
    const int idx  = bid >> 3;               // 0..95
    const int p    = idx >> 3;               // 0..11
    const int ct   = idx & 7;

    int rt, k0s, k0e;
    bool scaled = false;
    float* dst;
    if (half == 0) {
        if (p < 8) {
            rt = p; k0s = 0; k0e = (rt + 1) * 128; scaled = true;
            dst = out + (long)bz * 2097152 + (long)rt * 128 * 1024;
        } else {
            rt = p;  // 8..11
            k0s = 0; k0e = 1024;
            dst = out + (long)bz * 2097152 + (long)rt * 128 * 1024;
        }
    } else {
        if (p < 4) {
            rt = 12 + p; k0s = 0; k0e = 1024;
            dst = out + (long)bz * 2097152 + (long)rt * 128 * 1024;
        } else {
            rt = 4 + p;  // 8..15
            k0s = 1024; k0e = (rt + 1) * 128;
            dst = tmp1 + ((long)bz * 1024 + (long)(rt - 8) * 128) * 1024;
        }
    }

    __shared__ short lsA[2][128 * 32];
    __shared__ short lsB[2][128 * 32];

    const int tid  = threadIdx.x;
    const int wave = tid >> 6;
    const int lane = tid & 63;
    const int wr   = (wave >> 1) * 64;
    const int wc   = (wave &  1) * 64;
    const int srow = wave * 32 + (lane >> 2);
    const int scol = ((lane & 3) ^ ((lane >> 3) & 3)) * 8;   // T2 swizzle
    const int frow = lane & 15;
    const int fk   = ((lane >> 4) ^ ((lane >> 1) & 3)) * 8;

    const short* A = (const short*)P  + (long)bz * 4194304 + (long)rt * 128 * 2048;
    const short* B = (const short*)Vt + (long)bz * 2097152 + (long)ct * 128 * 2048;

    f32x4 acc[4][4] = {};

    for (int k0 = k0s; k0 < k0e; k0 += 64) {
        const short* ga = A + (long)srow * 2048 + k0 + scol;
        const short* gb = B + (long)srow * 2048 + k0 + scol;
        load_lds16(ga,                   &lsA[0][(wave * 32) * 32]);
        load_lds16(ga + 16L * 2048,      &lsA[0][(wave * 32 + 16) * 32]);
        load_lds16(ga + 32,              &lsA[1][(wave * 32) * 32]);
        load_lds16(ga + 16L * 2048 + 32, &lsA[1][(wave * 32 + 16) * 32]);
        load_lds16(gb,                   &lsB[0][(wave * 32) * 32]);
        load_lds16(gb + 16L * 2048,      &lsB[0][(wave * 32 + 16) * 32]);
        load_lds16(gb + 32,              &lsB[1][(wave * 32) * 32]);
        load_lds16(gb + 16L * 2048 + 32, &lsB[1][(wave * 32 + 16) * 32]);
        __syncthreads();

        #pragma unroll
        for (int sub = 0; sub < 2; ++sub) {
            bf16x8 af[4], bfr[4];
            #pragma unroll
            for (int m = 0; m < 4; ++m)
                af[m] = *(const bf16x8*)&lsA[sub][(wr + m * 16 + frow) * 32 + fk];
            #pragma unroll
            for (int n = 0; n < 4; ++n)
                bfr[n] = *(const bf16x8*)&lsB[sub][(wc + n * 16 + frow) * 32 + fk];
            #pragma unroll
            for (int m = 0; m < 4; ++m)
                #pragma unroll
                for (int n = 0; n < 4; ++n)
                    acc[m][n] = __builtin_amdgcn_mfma_f32_16x16x32_bf16(
                        af[m], bfr[n], acc[m][n], 0, 0, 0);
        }
        __syncthreads();
    }

    const int orow = (lane >> 4) * 4;
    const int ocol = lane & 15;
    if (scaled) {
        const float* il = Lbuf + bz * T_SEQ + (long)rt * 128;
        #pragma unroll
        for (int m = 0; m < 4; ++m)
            #pragma unroll
            for (int r = 0; r < 4; ++r) {
                const long lrow = wr + m * 16 + orow + r;
                const float s = 1.f / il[lrow];
                #pragma unroll
                for (int n = 0; n < 4; ++n)
                    dst[lrow * 1024 + ct * 128 + wc + n * 16 + ocol] =
                        acc[m][n][r] * s;
            }
    } else {
        #pragma unroll
        for (int m = 0; m < 4; ++m)
            #pragma unroll
            for (int r = 0; r < 4; ++r) {
                const long lrow = wr + m * 16 + orow + r;
                #pragma unroll
                for (int n = 0; n < 4; ++n)
                    dst[lrow * 1024 + ct * 128 + wc + n * 16 + ocol] = acc[m][n][r];
            }
    }
}

// ---------------------------------------------------------------- PV finish
// rows >= 1024 per batch: out = (out + tmp1) / l.
__global__ void pv_finish(float* __restrict__ out,
                          const float* __restrict__ tmp1,
                          const float* __restrict__ Lbuf) {
    const int g = blockIdx.x;                // 0..4095
    const int b = g >> 10;
    const int r = (g & 1023) + 1024;
    const int c = threadIdx.x * 4;
    const float s = 1.f / Lbuf[b * T_SEQ + r];
    float* po = out + (long)b * 2097152 + (long)r * 1024 + c;
    float4 o = *(const float4*)po;
    float4 t = *(const float4*)&tmp1[((long)b * 1024 + (r - 1024)) * 1024 + c];
    o.x = (o.x + t.x) * s; o.y = (o.y + t.y) * s;
    o.z = (o.z + t.z) * s; o.w = (o.w + t.w) * s;
    *(float4*)po = o;
}

// ---------------------------------------------------------------- launch
extern "C" void kernel_launch(void* const* d_in, const int* in_sizes, int n_in,
                              void* d_out, int out_size, void* d_ws, size_t ws_size,
                              hipStream_t stream) {
    const float* x  = (const float*)d_in[0];
    const float* Wq = (const float*)d_in[1];
    const float* Wk = (const float*)d_in[2];
    const float* Wv = (const float*)d_in[3];

    char* ws = (char*)d_ws;
    // workspace (bytes):
    //   xb   @ 0         : 16,777,216   (dead after QKV; tmp1 aliases)
    //   wb   @ 16777216  :  6,291,456
    //   qkv  @ 23068672  : 50,331,648   (Q|K cols used; V cols unwritten)
    //   vT   @ 73400320  : 16,777,216
    //   P    @ 90177536  : 33,554,432
    //   l    @ 123731968 :     32,768
    __hip_bfloat16* xb   = (__hip_bfloat16*)(ws);
    __hip_bfloat16* wb   = (__hip_bfloat16*)(ws + 16777216);
    __hip_bfloat16* qkv  = (__hip_bfloat16*)(ws + 23068672);
    __hip_bfloat16* vT   = (__hip_bfloat16*)(ws + 73400320);
    __hip_bfloat16* P    = (__hip_bfloat16*)(ws + 90177536);
    float*          Lbuf = (float*)        (ws + 123731968);
    float*          tmp1 = (float*)        (ws);              // aliases xb

    // 1) casts + Lbuf zero
    cast_all<<<dim3(11296), 256, 0, stream>>>(x, Wq, Wk, Wv, xb, wb, Lbuf);

    // 2) fused QKV; fat-wave 256x128 core. Q/K -> qkv, V -> vT transposed
    qkv_gemm<<<dim3(768), 256, 0, stream>>>(xb, wb, qkv, vT);

    // 3) P = exp(mask(QK^T)/32) bf16 + atomic rowsums; fat-wave triangle
    s_gemm<<<dim3(288), 256, 0, stream>>>(qkv, P, Lbuf);

    // 4) O = P @ V ; XCD-grouped split-K, direct rows scaled in-epilogue
    pv_split<<<dim3(768), 256, 0, stream>>>(
        P, vT, (float*)d_out, tmp1, Lbuf);

    // 5) combine + scale split rows
    pv_finish<<<dim3(4096), 256, 0, stream>>>((float*)d_out, tmp1, Lbuf);
}